// Round 12
// baseline (80.765 us; speedup 1.0000x reference)
//
#include <hip/hip_runtime.h>

#define NTOK 8192
#define DH   128
#define QBLK 256
#define KVB  64

typedef __attribute__((ext_vector_type(8)))  short bf16x8;
typedef __attribute__((ext_vector_type(16))) float f32x16;
typedef __attribute__((ext_vector_type(4)))  unsigned short u16x4;

typedef __attribute__((address_space(1))) const void gv_t;
typedef __attribute__((address_space(3))) void sv_t;

static __device__ __forceinline__ unsigned short f2bf(float x) {
  union { float f; unsigned int u; } a; a.f = x;
  unsigned int r = a.u + 0x7FFFu + ((a.u >> 16) & 1u);  // RNE
  return (unsigned short)(r >> 16);
}

static __device__ __forceinline__ unsigned pk2(float lo, float hi) {
  unsigned r;
  asm("v_cvt_pk_bf16_f32 %0, %1, %2" : "=v"(r) : "v"(lo), "v"(hi));
  return r;
}

static __device__ __forceinline__ f32x16 zero16() {
  f32x16 v;
  #pragma unroll
  for (int i = 0; i < 16; ++i) v[i] = 0.f;
  return v;
}

// ---------------------------------------------------------------------------
// Pre-pass: bf16 "LDS images" of K (row-major, swizzle (row&15)<<4 @16B) and
// V^T (128 d-rows x 128B, swizzle (d&15)<<3 @8B), tiled by 64 kv (16KB/tile).
// ---------------------------------------------------------------------------
__global__ __launch_bounds__(256)
void fa_prep(const float* __restrict__ Kg, const float* __restrict__ Vg,
             char* __restrict__ Kimg, char* __restrict__ Vimg)
{
  const int t = blockIdx.x;
  const int tid = threadIdx.x;

  { // K tile: 64 rows x 256B
    const int krow = tid >> 2;
    const int kcg  = (tid & 3) * 32;
    const float* src = Kg + ((size_t)t * KVB + krow) * DH + kcg;
    char* drow = Kimg + (size_t)t * 16384 + krow * 256;
    const int sw = (krow & 15) << 4;
    #pragma unroll
    for (int w = 0; w < 4; ++w) {
      float4 a = *reinterpret_cast<const float4*>(src + w * 8);
      float4 b = *reinterpret_cast<const float4*>(src + w * 8 + 4);
      union { bf16x8 v; unsigned short u[8]; } f;
      f.u[0] = f2bf(a.x); f.u[1] = f2bf(a.y); f.u[2] = f2bf(a.z); f.u[3] = f2bf(a.w);
      f.u[4] = f2bf(b.x); f.u[5] = f2bf(b.y); f.u[6] = f2bf(b.z); f.u[7] = f2bf(b.w);
      *reinterpret_cast<bf16x8*>(drow + ((kcg * 2 + w * 16) ^ sw)) = f.v;
    }
  }

  { // V^T tile: 128 d-rows x 128B, 4x4 register transpose per task
    #pragma unroll
    for (int it = 0; it < 2; ++it) {
      int task = tid + it * 256;            // 512 tasks of 4kv x 4d
      int kvl  = (task & 15) * 4;
      int d0   = (task >> 4) * 4;
      const float* src = Vg + ((size_t)t * KVB + kvl) * DH + d0;
      float4 r0 = *reinterpret_cast<const float4*>(src);
      float4 r1 = *reinterpret_cast<const float4*>(src + DH);
      float4 r2 = *reinterpret_cast<const float4*>(src + 2 * DH);
      float4 r3 = *reinterpret_cast<const float4*>(src + 3 * DH);
      char* base = Vimg + (size_t)t * 16384;
      const int bb = kvl * 2;
      { int d = d0 + 0;
        u16x4 w4 = (u16x4){f2bf(r0.x), f2bf(r1.x), f2bf(r2.x), f2bf(r3.x)};
        *reinterpret_cast<u16x4*>(base + d * 128 + (bb ^ ((d & 15) << 3))) = w4; }
      { int d = d0 + 1;
        u16x4 w4 = (u16x4){f2bf(r0.y), f2bf(r1.y), f2bf(r2.y), f2bf(r3.y)};
        *reinterpret_cast<u16x4*>(base + d * 128 + (bb ^ ((d & 15) << 3))) = w4; }
      { int d = d0 + 2;
        u16x4 w4 = (u16x4){f2bf(r0.z), f2bf(r1.z), f2bf(r2.z), f2bf(r3.z)};
        *reinterpret_cast<u16x4*>(base + d * 128 + (bb ^ ((d & 15) << 3))) = w4; }
      { int d = d0 + 3;
        u16x4 w4 = (u16x4){f2bf(r0.w), f2bf(r1.w), f2bf(r2.w), f2bf(r3.w)};
        *reinterpret_cast<u16x4*>(base + d * 128 + (bb ^ ((d & 15) << 3))) = w4; }
    }
  }
}

// ---------------------------------------------------------------------------
// softmax over one 32-kv half (R9-proven): shfl-free steady state, tree
// pmax/psum, defer-max (T13), fused exp->cvt_pk.
// ---------------------------------------------------------------------------
static __device__ __forceinline__ void softmax_half(
    const f32x16& st, float& m_run, float& l_run, f32x16* oacc,
    bf16x8& pfa, bf16x8& pfb)
{
  float a0 = fmaxf(st[0],  st[1]),  a1 = fmaxf(st[2],  st[3]);
  float a2 = fmaxf(st[4],  st[5]),  a3 = fmaxf(st[6],  st[7]);
  float a4 = fmaxf(st[8],  st[9]),  a5 = fmaxf(st[10], st[11]);
  float a6 = fmaxf(st[12], st[13]), a7 = fmaxf(st[14], st[15]);
  float b0 = fmaxf(a0, a1), b1 = fmaxf(a2, a3);
  float b2 = fmaxf(a4, a5), b3 = fmaxf(a6, a7);
  float pmax = fmaxf(fmaxf(b0, b1), fmaxf(b2, b3));
  if (!__all(pmax <= m_run + 8.f)) {            // rare after warm-up (T13)
    pmax = fmaxf(pmax, __shfl_xor(pmax, 32));   // pair-max (uniform branch)
    const float m_new = fmaxf(m_run, pmax);
    const float corr  = (m_run > -1e30f) ? exp2f(m_run - m_new) : 0.f;
    l_run *= corr;
    #pragma unroll
    for (int i = 0; i < 4; ++i) oacc[i] = oacc[i] * corr;
    m_run = m_new;
  }
  float e[16];
  #pragma unroll
  for (int r = 0; r < 16; ++r) e[r] = exp2f(st[r] - m_run);
  float s0 = (e[0] + e[1])   + (e[2] + e[3]);
  float s1 = (e[4] + e[5])   + (e[6] + e[7]);
  float s2 = (e[8] + e[9])   + (e[10] + e[11]);
  float s3 = (e[12] + e[13]) + (e[14] + e[15]);
  l_run += (s0 + s1) + (s2 + s3);               // per-lane partial
  union { bf16x8 v; unsigned u[4]; } fa, fb;
  fa.u[0] = pk2(e[0],  e[1]);  fa.u[1] = pk2(e[2],  e[3]);
  fa.u[2] = pk2(e[4],  e[5]);  fa.u[3] = pk2(e[6],  e[7]);
  fb.u[0] = pk2(e[8],  e[9]);  fb.u[1] = pk2(e[10], e[11]);
  fb.u[2] = pk2(e[12], e[13]); fb.u[3] = pk2(e[14], e[15]);
  pfa = fa.v; pfb = fb.v;
}

// ---------------------------------------------------------------------------
// Flash fwd: 4 waves x 64 q (two 32-q subtiles A/B per wave), QBLK=256,
// 32x32x16 MFMA. Every K/V fragment read from LDS feeds TWO MFMAs (A and B)
// -> LDS-read instructions per unit work halved vs the 32-q/wave structure.
// 1 block/CU, 1 wave/SIMD (VGPR ~300, intentional: R10 proved extra waves
// don't help; registers do). R9-proven loop: depth-2 DMA prefetch, counted
// vmcnt(8), raw barriers, no drain in loop.
// ---------------------------------------------------------------------------
__global__ __launch_bounds__(256, 1)
void fa_fwd(const float* __restrict__ Qg, const char* __restrict__ Kimg,
            const char* __restrict__ Vimg, float* __restrict__ Od,
            float* __restrict__ Mp, float* __restrict__ Lp,
            int ksplit, int chunk_len)
{
  __shared__ __align__(16) char smem[2][32768];   // [buf][K 16KB | V 16KB]
  const int tid  = threadIdx.x;
  const int lane = tid & 63;
  const int wv   = tid >> 6;
  const int l31  = lane & 31;
  const int hi   = lane >> 5;

  const int q0blk = blockIdx.x * QBLK;
  const int qA    = q0blk + wv * 64 + l31;        // subtile A
  const int qB    = qA + 32;                      // subtile B
  const int chunk = blockIdx.y;
  const float QSCALE = 0.1275313310087464f;       // rsqrt(128) * log2(e)

  const int tile0 = (chunk * chunk_len) >> 6;
  const int nst   = chunk_len >> 6;

  // ---- Q fragments FIRST (their waits retire before the loop).
  bf16x8 qfA[8], qfB[8];
  {
    const float* qsA = Qg + (size_t)qA * DH + hi * 8;
    const float* qsB = Qg + (size_t)qB * DH + hi * 8;
    #pragma unroll
    for (int kc = 0; kc < 8; ++kc) {
      float4 a = *reinterpret_cast<const float4*>(qsA + kc * 16);
      float4 b = *reinterpret_cast<const float4*>(qsA + kc * 16 + 4);
      union { bf16x8 v; unsigned u[4]; } f;
      f.u[0] = pk2(a.x * QSCALE, a.y * QSCALE);
      f.u[1] = pk2(a.z * QSCALE, a.w * QSCALE);
      f.u[2] = pk2(b.x * QSCALE, b.y * QSCALE);
      f.u[3] = pk2(b.z * QSCALE, b.w * QSCALE);
      qfA[kc] = f.v;
      float4 c = *reinterpret_cast<const float4*>(qsB + kc * 16);
      float4 d = *reinterpret_cast<const float4*>(qsB + kc * 16 + 4);
      f.u[0] = pk2(c.x * QSCALE, c.y * QSCALE);
      f.u[1] = pk2(c.z * QSCALE, c.w * QSCALE);
      f.u[2] = pk2(d.x * QSCALE, d.y * QSCALE);
      f.u[3] = pk2(d.z * QSCALE, d.w * QSCALE);
      qfB[kc] = f.v;
    }
  }

  // Per-wave DMA roles: waves 0,1 = K halves; waves 2,3 = V halves (8KB each,
  // 8 x 1KB global_load_lds_dwordx4 per wave per tile).
  const char* gbase = (wv < 2 ? Kimg : Vimg);
  const size_t goff = (size_t)(wv & 1) * 8192 + (size_t)lane * 16;
  const int    loff = (wv < 2 ? 0 : 16384) + (wv & 1) * 8192;

#define STAGE(B, T) do {                                                      \
    const char* _s = gbase + (size_t)(T) * 16384 + goff;                      \
    char* _d = &smem[B][loff];                                                \
    _Pragma("unroll")                                                         \
    for (int _i = 0; _i < 8; ++_i)                                            \
      __builtin_amdgcn_global_load_lds((gv_t*)(_s + _i * 1024),               \
                                       (sv_t*)(_d + _i * 1024), 16, 0, 0);    \
  } while (0)

  STAGE(0, tile0);
  if (nst > 1) STAGE(1, tile0 + 1);

  f32x16 oaccA[4], oaccB[4];
  #pragma unroll
  for (int i = 0; i < 4; ++i) { oaccA[i] = zero16(); oaccB[i] = zero16(); }
  float mA = -INFINITY, lA = 0.f;
  float mB = -INFINITY, lB = 0.f;

  int cur = 0;
  for (int t = 0; t < nst; ++t) {
    // own 8 DMA loads for tile t done; tile t+1's 8 stay in flight (T4).
    if (t + 1 < nst) asm volatile("s_waitcnt vmcnt(8)" ::: "memory");
    else             asm volatile("s_waitcnt vmcnt(0)" ::: "memory");
    __builtin_amdgcn_sched_barrier(0);
    __builtin_amdgcn_s_barrier();          // cross-wave: tile t fully in LDS

    const char* smK = smem[cur];
    const char* smV = smem[cur] + 16384;
    const int swk = (l31 & 15) << 4;
    const int swv = (l31 & 15) << 3;

    // ---- QK^T: each K fragment read feeds both subtiles (A and B).
    f32x16 sA0 = zero16(), sA1 = zero16(), sB0 = zero16(), sB1 = zero16();
    __builtin_amdgcn_s_setprio(1);
    #pragma unroll
    for (int kc = 0; kc < 8; ++kc) {
      const int cb = (kc * 32 + hi * 16) ^ swk;
      bf16x8 a0 = *reinterpret_cast<const bf16x8*>(smK + l31 * 256 + cb);
      sA0 = __builtin_amdgcn_mfma_f32_32x32x16_bf16(a0, qfA[kc], sA0, 0, 0, 0);
      sB0 = __builtin_amdgcn_mfma_f32_32x32x16_bf16(a0, qfB[kc], sB0, 0, 0, 0);
      bf16x8 a1 = *reinterpret_cast<const bf16x8*>(smK + (l31 + 32) * 256 + cb);
      sA1 = __builtin_amdgcn_mfma_f32_32x32x16_bf16(a1, qfA[kc], sA1, 0, 0, 0);
      sB1 = __builtin_amdgcn_mfma_f32_32x32x16_bf16(a1, qfB[kc], sB1, 0, 0, 0);
    }
    __builtin_amdgcn_s_setprio(0);

    // ---- softmax: 4 halves (A0, A1, B0, B1)
    bf16x8 pA0a, pA0b, pA1a, pA1b, pB0a, pB0b, pB1a, pB1b;
    softmax_half(sA0, mA, lA, oaccA, pA0a, pA0b);
    softmax_half(sA1, mA, lA, oaccA, pA1a, pA1b);
    softmax_half(sB0, mB, lB, oaccB, pB0a, pB0b);
    softmax_half(sB1, mB, lB, oaccB, pB1a, pB1b);

    // ---- PV: each V fragment read feeds both subtiles.
    __builtin_amdgcn_s_setprio(1);
    #pragma unroll
    for (int c = 0; c < 4; ++c) {
      const bf16x8 pbA = (c == 0) ? pA0a : (c == 1) ? pA0b : (c == 2) ? pA1a : pA1b;
      const bf16x8 pbB = (c == 0) ? pB0a : (c == 1) ? pB0b : (c == 2) ? pB1a : pB1b;
      #pragma unroll
      for (int dt = 0; dt < 4; ++dt) {
        const char* vb = smV + (dt * 32 + l31) * 128;
        union { bf16x8 v; u16x4 h[2]; } a;
        a.h[0] = *reinterpret_cast<const u16x4*>(vb + ((c * 32 + 8 * hi) ^ swv));
        a.h[1] = *reinterpret_cast<const u16x4*>(vb + ((c * 32 + 16 + 8 * hi) ^ swv));
        oaccA[dt] = __builtin_amdgcn_mfma_f32_32x32x16_bf16(a.v, pbA, oaccA[dt], 0, 0, 0);
        oaccB[dt] = __builtin_amdgcn_mfma_f32_32x32x16_bf16(a.v, pbB, oaccB[dt], 0, 0, 0);
      }
    }
    __builtin_amdgcn_s_setprio(0);

    __builtin_amdgcn_s_barrier();          // all waves done reading buf[cur]
    if (t + 2 < nst) STAGE(cur, tile0 + t + 2);   // refill freed buffer
    cur ^= 1;
  }
#undef STAGE

  // ---- combine per-lane l partials (one shfl per subtile).
  const float lAt = lA + __shfl_xor(lA, 32);
  const float lBt = lB + __shfl_xor(lB, 32);
  const float scA = (ksplit == 1) ? (1.f / lAt) : 1.f;
  const float scB = (ksplit == 1) ? (1.f / lBt) : 1.f;
  float* dstB = (ksplit == 1) ? Od : Od + (size_t)chunk * NTOK * DH;

  // ---- epilogue (R9-proven pattern), run twice through the wave's 16KB
  //      region: subtile A then B. Sector-perfect stores.
  char* base = &smem[0][0] + wv * 16384;          // [d][q32] f32, 128B rows
  const int qloc4 = lane >> 2;                    // 0..15
  const int s4    = lane & 3;                     // 16B slot in 64B sector

#define EPI(OACC, SC, QOFF) do {                                               \
    _Pragma("unroll")                                                          \
    for (int dt = 0; dt < 4; ++dt)                                             \
      _Pragma("unroll")                                                        \
      for (int rg = 0; rg < 4; ++rg)                                           \
        _Pragma("unroll")                                                      \
        for (int j = 0; j < 4; ++j) {                                          \
          const int d = dt * 32 + rg * 8 + hi * 4 + j;                         \
          *reinterpret_cast<float*>(base + d * 128 + l31 * 4) =                \
              (OACC)[dt][rg * 4 + j] * (SC);                                   \
        }                                                                      \
    asm volatile("s_waitcnt lgkmcnt(0)" ::: "memory");                         \
    __builtin_amdgcn_sched_barrier(0);                                         \
    _Pragma("unroll")                                                          \
    for (int qh = 0; qh < 2; ++qh) {                                           \
      const int qloc = qh * 16 + qloc4;                                        \
      float* dst = dstB + (size_t)(q0blk + wv * 64 + (QOFF) + qloc) * DH;      \
      _Pragma("unroll")                                                        \
      for (int i = 0; i < 8; ++i) {                                            \
        const int dd = s4 * 4 + i * 16;                                        \
        float4 v;                                                              \
        v.x = *reinterpret_cast<float*>(base + (dd + 0) * 128 + qloc * 4);     \
        v.y = *reinterpret_cast<float*>(base + (dd + 1) * 128 + qloc * 4);     \
        v.z = *reinterpret_cast<float*>(base + (dd + 2) * 128 + qloc * 4);     \
        v.w = *reinterpret_cast<float*>(base + (dd + 3) * 128 + qloc * 4);     \
        *reinterpret_cast<float4*>(dst + dd) = v;                              \
      }                                                                        \
    }                                                                          \
    asm volatile("s_waitcnt lgkmcnt(0)" ::: "memory");                         \
    __builtin_amdgcn_sched_barrier(0);                                         \
  } while (0)

  EPI(oaccA, scA, 0);
  EPI(oaccB, scB, 32);
#undef EPI

  if (ksplit > 1 && lane < 32) {
    const int qgA = q0blk + wv * 64 + lane;
    Mp[chunk * NTOK + qgA] = mA;
    Lp[chunk * NTOK + qgA] = lAt;
    Mp[chunk * NTOK + qgA + 32] = mB;
    Lp[chunk * NTOK + qgA + 32] = lBt;
  }
}

__global__ __launch_bounds__(256)
void fa_combine(const float* __restrict__ Op, const float* __restrict__ Mp,
                const float* __restrict__ Lp, float* __restrict__ out, int ksplit)
{
  const int gid = blockIdx.x * 256 + threadIdx.x;   // N*D/4 threads
  const int q   = gid >> 5;
  const int dv  = (gid & 31) * 4;
  float mx = -INFINITY;
  for (int c = 0; c < ksplit; ++c) mx = fmaxf(mx, Mp[c * NTOK + q]);
  float den = 0.f;
  float ax = 0.f, ay = 0.f, az = 0.f, aw = 0.f;
  for (int c = 0; c < ksplit; ++c) {
    const float w = exp2f(Mp[c * NTOK + q] - mx);
    den += w * Lp[c * NTOK + q];
    float4 o = *reinterpret_cast<const float4*>(Op + (size_t)c * NTOK * DH + (size_t)q * DH + dv);
    ax += w * o.x; ay += w * o.y; az += w * o.z; aw += w * o.w;
  }
  const float r = 1.f / den;
  float4 res; res.x = ax * r; res.y = ay * r; res.z = az * r; res.w = aw * r;
  *reinterpret_cast<float4*>(out + (size_t)q * DH + dv) = res;
}

extern "C" void kernel_launch(void* const* d_in, const int* in_sizes, int n_in,
                              void* d_out, int out_size, void* d_ws, size_t ws_size,
                              hipStream_t stream)
{
  const float* Q = (const float*)d_in[0];
  const float* K = (const float*)d_in[1];
  const float* V = (const float*)d_in[2];
  float* out = (float*)d_out;

  auto need = [](size_t ks) {
    return ks * (size_t)NTOK * DH * 4 + 2 * ks * (size_t)NTOK * 4;
  };
  int KS = (ws_size >= need(8)) ? 8 : (ws_size >= need(4)) ? 4 : 2;

  // K/V bf16 images live in d_out (4 MiB); combine overwrites d_out at the end.
  char* Kimg = (char*)d_out;
  char* Vimg = Kimg + (size_t)NTOK * 256;          // 2 MiB each

  float* Op = (float*)d_ws;
  float* Mp = Op + (size_t)KS * NTOK * DH;
  float* Lp = Mp + (size_t)KS * NTOK;

  fa_prep<<<NTOK / KVB, 256, 0, stream>>>(K, V, Kimg, Vimg);
  fa_fwd<<<dim3(NTOK / QBLK, KS), 256, 0, stream>>>(Q, Kimg, Vimg, Op, Mp, Lp,
                                                    KS, NTOK / KS);
  fa_combine<<<NTOK * DH / 4 / 256, 256, 0, stream>>>(Op, Mp, Lp, out, KS);
}

// Round 13
// 62.229 us; speedup vs baseline: 1.2979x; 1.2979x over previous
//
#include <hip/hip_runtime.h>

#define NTOK 8192
#define DH   128
#define QBLK 128
#define KVB  64

typedef __attribute__((ext_vector_type(8)))  short bf16x8;
typedef __attribute__((ext_vector_type(16))) float f32x16;
typedef __attribute__((ext_vector_type(4)))  unsigned short u16x4;
typedef __attribute__((ext_vector_type(4)))  _Float16 h16x4;

typedef __attribute__((address_space(1))) const void gv_t;
typedef __attribute__((address_space(3))) void sv_t;

static __device__ __forceinline__ unsigned short f2bf(float x) {
  union { float f; unsigned int u; } a; a.f = x;
  unsigned int r = a.u + 0x7FFFu + ((a.u >> 16) & 1u);  // RNE
  return (unsigned short)(r >> 16);
}

static __device__ __forceinline__ unsigned pk2(float lo, float hi) {
  unsigned r;
  asm("v_cvt_pk_bf16_f32 %0, %1, %2" : "=v"(r) : "v"(lo), "v"(hi));
  return r;
}

static __device__ __forceinline__ float fexp2(float x) {
  float r;
  asm("v_exp_f32 %0, %1" : "=v"(r) : "v"(x));
  return r;
}

static __device__ __forceinline__ f32x16 zero16() {
  f32x16 v;
  #pragma unroll
  for (int i = 0; i < 16; ++i) v[i] = 0.f;
  return v;
}

// ---------------------------------------------------------------------------
// Pre-pass: bf16 "LDS images" of K (row-major, swizzle (row&15)<<4 @16B) and
// V^T (128 d-rows x 128B, swizzle (d&15)<<3 @8B), tiled by 64 kv (16KB/tile).
// ---------------------------------------------------------------------------
__global__ __launch_bounds__(256)
void fa_prep(const float* __restrict__ Kg, const float* __restrict__ Vg,
             char* __restrict__ Kimg, char* __restrict__ Vimg)
{
  const int t = blockIdx.x;
  const int tid = threadIdx.x;

  { // K tile: 64 rows x 256B
    const int krow = tid >> 2;
    const int kcg  = (tid & 3) * 32;
    const float* src = Kg + ((size_t)t * KVB + krow) * DH + kcg;
    char* drow = Kimg + (size_t)t * 16384 + krow * 256;
    const int sw = (krow & 15) << 4;
    #pragma unroll
    for (int w = 0; w < 4; ++w) {
      float4 a = *reinterpret_cast<const float4*>(src + w * 8);
      float4 b = *reinterpret_cast<const float4*>(src + w * 8 + 4);
      union { bf16x8 v; unsigned short u[8]; } f;
      f.u[0] = f2bf(a.x); f.u[1] = f2bf(a.y); f.u[2] = f2bf(a.z); f.u[3] = f2bf(a.w);
      f.u[4] = f2bf(b.x); f.u[5] = f2bf(b.y); f.u[6] = f2bf(b.z); f.u[7] = f2bf(b.w);
      *reinterpret_cast<bf16x8*>(drow + ((kcg * 2 + w * 16) ^ sw)) = f.v;
    }
  }

  { // V^T tile: 128 d-rows x 128B, 4x4 register transpose per task
    #pragma unroll
    for (int it = 0; it < 2; ++it) {
      int task = tid + it * 256;            // 512 tasks of 4kv x 4d
      int kvl  = (task & 15) * 4;
      int d0   = (task >> 4) * 4;
      const float* src = Vg + ((size_t)t * KVB + kvl) * DH + d0;
      float4 r0 = *reinterpret_cast<const float4*>(src);
      float4 r1 = *reinterpret_cast<const float4*>(src + DH);
      float4 r2 = *reinterpret_cast<const float4*>(src + 2 * DH);
      float4 r3 = *reinterpret_cast<const float4*>(src + 3 * DH);
      char* base = Vimg + (size_t)t * 16384;
      const int bb = kvl * 2;
      { int d = d0 + 0;
        u16x4 w4 = (u16x4){f2bf(r0.x), f2bf(r1.x), f2bf(r2.x), f2bf(r3.x)};
        *reinterpret_cast<u16x4*>(base + d * 128 + (bb ^ ((d & 15) << 3))) = w4; }
      { int d = d0 + 1;
        u16x4 w4 = (u16x4){f2bf(r0.y), f2bf(r1.y), f2bf(r2.y), f2bf(r3.y)};
        *reinterpret_cast<u16x4*>(base + d * 128 + (bb ^ ((d & 15) << 3))) = w4; }
      { int d = d0 + 2;
        u16x4 w4 = (u16x4){f2bf(r0.z), f2bf(r1.z), f2bf(r2.z), f2bf(r3.z)};
        *reinterpret_cast<u16x4*>(base + d * 128 + (bb ^ ((d & 15) << 3))) = w4; }
      { int d = d0 + 3;
        u16x4 w4 = (u16x4){f2bf(r0.w), f2bf(r1.w), f2bf(r2.w), f2bf(r3.w)};
        *reinterpret_cast<u16x4*>(base + d * 128 + (bb ^ ((d & 15) << 3))) = w4; }
    }
  }
}

// ---------------------------------------------------------------------------
// softmax over one 32-kv half (R9-proven): shfl-free steady state, tree
// pmax/psum, defer-max (T13), fused exp->cvt_pk. m_run init = -30000 so
// corr = exp2(m_run - m_new) flushes to 0 on first tile (no guard branch).
// ---------------------------------------------------------------------------
static __device__ __forceinline__ void softmax_half(
    const f32x16& st, float& m_run, float& l_run, f32x16* oacc,
    bf16x8& pfa, bf16x8& pfb)
{
  float a0 = fmaxf(st[0],  st[1]),  a1 = fmaxf(st[2],  st[3]);
  float a2 = fmaxf(st[4],  st[5]),  a3 = fmaxf(st[6],  st[7]);
  float a4 = fmaxf(st[8],  st[9]),  a5 = fmaxf(st[10], st[11]);
  float a6 = fmaxf(st[12], st[13]), a7 = fmaxf(st[14], st[15]);
  float b0 = fmaxf(a0, a1), b1 = fmaxf(a2, a3);
  float b2 = fmaxf(a4, a5), b3 = fmaxf(a6, a7);
  float pmax = fmaxf(fmaxf(b0, b1), fmaxf(b2, b3));
  if (!__all(pmax <= m_run + 8.f)) {            // rare after warm-up (T13)
    pmax = fmaxf(pmax, __shfl_xor(pmax, 32));   // pair-max (uniform branch)
    const float m_new = fmaxf(m_run, pmax);
    const float corr  = fexp2(m_run - m_new);   // ==0 on first tile
    l_run *= corr;
    #pragma unroll
    for (int i = 0; i < 4; ++i) oacc[i] = oacc[i] * corr;
    m_run = m_new;
  }
  float e[16];
  #pragma unroll
  for (int r = 0; r < 16; ++r) e[r] = fexp2(st[r] - m_run);
  float s0 = (e[0] + e[1])   + (e[2] + e[3]);
  float s1 = (e[4] + e[5])   + (e[6] + e[7]);
  float s2 = (e[8] + e[9])   + (e[10] + e[11]);
  float s3 = (e[12] + e[13]) + (e[14] + e[15]);
  l_run += (s0 + s1) + (s2 + s3);               // per-lane partial
  union { bf16x8 v; unsigned u[4]; } fa, fb;
  fa.u[0] = pk2(e[0],  e[1]);  fa.u[1] = pk2(e[2],  e[3]);
  fa.u[2] = pk2(e[4],  e[5]);  fa.u[3] = pk2(e[6],  e[7]);
  fb.u[0] = pk2(e[8],  e[9]);  fb.u[1] = pk2(e[10], e[11]);
  fb.u[2] = pk2(e[12], e[13]); fb.u[3] = pk2(e[14], e[15]);
  pfa = fa.v; pfb = fb.v;
}

// ---------------------------------------------------------------------------
// Flash fwd: 4 waves x 32 q (QBLK=128), 32x32x16 MFMA. R9 loop verbatim
// (proven 58.7us): depth-2 DMA prefetch, counted vmcnt(8), raw barriers.
// Split-K partials stored as f16 (halves partial-O HBM traffic; defer-max
// bounds values ~O(1e3) << f16 max, added err ~2^-11 relative).
// ---------------------------------------------------------------------------
__global__ __launch_bounds__(256, 2)
void fa_fwd(const float* __restrict__ Qg, const char* __restrict__ Kimg,
            const char* __restrict__ Vimg, float* __restrict__ Od,
            _Float16* __restrict__ Oh, float* __restrict__ Mp,
            float* __restrict__ Lp, int ksplit, int chunk_len)
{
  __shared__ __align__(16) char smem[2][32768];   // [buf][K 16KB | V 16KB]
  const int tid  = threadIdx.x;
  const int lane = tid & 63;
  const int wv   = tid >> 6;
  const int l31  = lane & 31;
  const int hi   = lane >> 5;

  const int q0blk = blockIdx.x * QBLK;
  const int q     = q0blk + wv * 32 + l31;
  const int chunk = blockIdx.y;
  const float QSCALE = 0.1275313310087464f;       // rsqrt(128) * log2(e)

  const int tile0 = (chunk * chunk_len) >> 6;
  const int nst   = chunk_len >> 6;

  // ---- Q fragments FIRST (their waits retire before the loop).
  bf16x8 qf[8];
  {
    const float* qs = Qg + (size_t)q * DH + hi * 8;
    #pragma unroll
    for (int kc = 0; kc < 8; ++kc) {
      float4 a = *reinterpret_cast<const float4*>(qs + kc * 16);
      float4 b = *reinterpret_cast<const float4*>(qs + kc * 16 + 4);
      union { bf16x8 v; unsigned u[4]; } f;
      f.u[0] = pk2(a.x * QSCALE, a.y * QSCALE);
      f.u[1] = pk2(a.z * QSCALE, a.w * QSCALE);
      f.u[2] = pk2(b.x * QSCALE, b.y * QSCALE);
      f.u[3] = pk2(b.z * QSCALE, b.w * QSCALE);
      qf[kc] = f.v;
    }
  }

  // Per-wave DMA roles: waves 0,1 = K halves; waves 2,3 = V halves (8KB each,
  // 8 x 1KB global_load_lds_dwordx4 per wave per tile).
  const char* gbase = (wv < 2 ? Kimg : Vimg);
  const size_t goff = (size_t)(wv & 1) * 8192 + (size_t)lane * 16;
  const int    loff = (wv < 2 ? 0 : 16384) + (wv & 1) * 8192;

#define STAGE(B, T) do {                                                      \
    const char* _s = gbase + (size_t)(T) * 16384 + goff;                      \
    char* _d = &smem[B][loff];                                                \
    _Pragma("unroll")                                                         \
    for (int _i = 0; _i < 8; ++_i)                                            \
      __builtin_amdgcn_global_load_lds((gv_t*)(_s + _i * 1024),               \
                                       (sv_t*)(_d + _i * 1024), 16, 0, 0);    \
  } while (0)

  STAGE(0, tile0);
  if (nst > 1) STAGE(1, tile0 + 1);

  f32x16 oacc[4];
  #pragma unroll
  for (int i = 0; i < 4; ++i) oacc[i] = zero16();
  float m_run = -30000.f, l_run = 0.f;

  int cur = 0;
  for (int t = 0; t < nst; ++t) {
    // own 8 DMA loads for tile t done; tile t+1's 8 stay in flight (T4).
    if (t + 1 < nst) asm volatile("s_waitcnt vmcnt(8)" ::: "memory");
    else             asm volatile("s_waitcnt vmcnt(0)" ::: "memory");
    __builtin_amdgcn_sched_barrier(0);
    __builtin_amdgcn_s_barrier();          // cross-wave: tile t fully in LDS

    const char* smK = smem[cur];
    const char* smV = smem[cur] + 16384;
    const int swk = (l31 & 15) << 4;
    const int swv = (l31 & 15) << 3;

    // ---- QK^T both halves (two independent MFMA chains)
    f32x16 st0 = zero16(), st1 = zero16();
    __builtin_amdgcn_s_setprio(1);
    #pragma unroll
    for (int kc = 0; kc < 8; ++kc) {
      const int cb = (kc * 32 + hi * 16) ^ swk;
      bf16x8 a0 = *reinterpret_cast<const bf16x8*>(smK + l31 * 256 + cb);
      st0 = __builtin_amdgcn_mfma_f32_32x32x16_bf16(a0, qf[kc], st0, 0, 0, 0);
      bf16x8 a1 = *reinterpret_cast<const bf16x8*>(smK + (l31 + 32) * 256 + cb);
      st1 = __builtin_amdgcn_mfma_f32_32x32x16_bf16(a1, qf[kc], st1, 0, 0, 0);
    }
    __builtin_amdgcn_s_setprio(0);

    // ---- half 0: softmax (VALU, overlaps st1 MFMAs) then PV kv 0..31
    bf16x8 pf0a, pf0b;
    softmax_half(st0, m_run, l_run, oacc, pf0a, pf0b);
    __builtin_amdgcn_s_setprio(1);
    #pragma unroll
    for (int c = 0; c < 2; ++c) {
      const bf16x8 pb = c ? pf0b : pf0a;
      #pragma unroll
      for (int dt = 0; dt < 4; ++dt) {
        const char* vb = smV + (dt * 32 + l31) * 128;
        union { bf16x8 v; u16x4 h[2]; } a;
        a.h[0] = *reinterpret_cast<const u16x4*>(vb + ((c * 32 + 8 * hi) ^ swv));
        a.h[1] = *reinterpret_cast<const u16x4*>(vb + ((c * 32 + 16 + 8 * hi) ^ swv));
        oacc[dt] = __builtin_amdgcn_mfma_f32_32x32x16_bf16(a.v, pb, oacc[dt], 0, 0, 0);
      }
    }
    __builtin_amdgcn_s_setprio(0);

    // ---- half 1: softmax (overlaps PV0 MFMAs) then PV kv 32..63
    bf16x8 pf1a, pf1b;
    softmax_half(st1, m_run, l_run, oacc, pf1a, pf1b);
    __builtin_amdgcn_s_setprio(1);
    #pragma unroll
    for (int c = 2; c < 4; ++c) {
      const bf16x8 pb = (c & 1) ? pf1b : pf1a;
      #pragma unroll
      for (int dt = 0; dt < 4; ++dt) {
        const char* vb = smV + (dt * 32 + l31) * 128;
        union { bf16x8 v; u16x4 h[2]; } a;
        a.h[0] = *reinterpret_cast<const u16x4*>(vb + ((c * 32 + 8 * hi) ^ swv));
        a.h[1] = *reinterpret_cast<const u16x4*>(vb + ((c * 32 + 16 + 8 * hi) ^ swv));
        oacc[dt] = __builtin_amdgcn_mfma_f32_32x32x16_bf16(a.v, pb, oacc[dt], 0, 0, 0);
      }
    }
    __builtin_amdgcn_s_setprio(0);

    __builtin_amdgcn_s_barrier();          // all waves done reading buf[cur]
    if (t + 2 < nst) STAGE(cur, tile0 + t + 2);   // refill freed buffer
    cur ^= 1;
  }
#undef STAGE

  // ---- combine per-lane l partials (the only steady-state shfl, once).
  const float l_tot = l_run + __shfl_xor(l_run, 32);

  // ---- epilogue: per-wave 16KB LDS transpose (f32) -> coalesced stores.
  char* base = &smem[0][0] + wv * 16384;          // [d][q32] f32, 128B rows
  const float scale = (ksplit == 1) ? (1.f / l_tot) : 1.f;
  #pragma unroll
  for (int dt = 0; dt < 4; ++dt)
    #pragma unroll
    for (int rg = 0; rg < 4; ++rg)
      #pragma unroll
      for (int j = 0; j < 4; ++j) {
        const int d = dt * 32 + rg * 8 + hi * 4 + j;
        *reinterpret_cast<float*>(base + d * 128 + l31 * 4) =
            oacc[dt][rg * 4 + j] * scale;
      }
  asm volatile("s_waitcnt lgkmcnt(0)" ::: "memory");
  __builtin_amdgcn_sched_barrier(0);
  const int qloc4 = lane >> 2;                    // 0..15
  const int s4    = lane & 3;                     // 16B f32 slot / 8B f16 slot
  if (ksplit == 1) {
    #pragma unroll
    for (int qh = 0; qh < 2; ++qh) {
      const int qloc = qh * 16 + qloc4;
      float* dst = Od + (size_t)(q0blk + wv * 32 + qloc) * DH;
      #pragma unroll
      for (int i = 0; i < 8; ++i) {
        const int dd = s4 * 4 + i * 16;
        float4 v;
        v.x = *reinterpret_cast<float*>(base + (dd + 0) * 128 + qloc * 4);
        v.y = *reinterpret_cast<float*>(base + (dd + 1) * 128 + qloc * 4);
        v.z = *reinterpret_cast<float*>(base + (dd + 2) * 128 + qloc * 4);
        v.w = *reinterpret_cast<float*>(base + (dd + 3) * 128 + qloc * 4);
        *reinterpret_cast<float4*>(dst + dd) = v;
      }
    }
  } else {
    _Float16* dstB = Oh + (size_t)chunk * NTOK * DH;
    #pragma unroll
    for (int qh = 0; qh < 2; ++qh) {
      const int qloc = qh * 16 + qloc4;
      _Float16* dst = dstB + (size_t)(q0blk + wv * 32 + qloc) * DH;
      #pragma unroll
      for (int i = 0; i < 8; ++i) {
        const int dd = s4 * 4 + i * 16;
        h16x4 v;
        v.x = (_Float16)*reinterpret_cast<float*>(base + (dd + 0) * 128 + qloc * 4);
        v.y = (_Float16)*reinterpret_cast<float*>(base + (dd + 1) * 128 + qloc * 4);
        v.z = (_Float16)*reinterpret_cast<float*>(base + (dd + 2) * 128 + qloc * 4);
        v.w = (_Float16)*reinterpret_cast<float*>(base + (dd + 3) * 128 + qloc * 4);
        *reinterpret_cast<h16x4*>(dst + dd) = v;  // 8B/lane, fully coalesced
      }
    }
    if (lane < 32) {
      const int qg = q0blk + wv * 32 + lane;
      Mp[chunk * NTOK + qg] = m_run;
      Lp[chunk * NTOK + qg] = l_tot;
    }
  }
}

__global__ __launch_bounds__(256)
void fa_combine(const _Float16* __restrict__ Oh, const float* __restrict__ Mp,
                const float* __restrict__ Lp, float* __restrict__ out, int ksplit)
{
  const int gid = blockIdx.x * 256 + threadIdx.x;   // N*D/4 threads
  const int q   = gid >> 5;
  const int dv  = (gid & 31) * 4;
  float mx = -INFINITY;
  for (int c = 0; c < ksplit; ++c) mx = fmaxf(mx, Mp[c * NTOK + q]);
  float den = 0.f;
  float ax = 0.f, ay = 0.f, az = 0.f, aw = 0.f;
  for (int c = 0; c < ksplit; ++c) {
    const float w = fexp2(Mp[c * NTOK + q] - mx);
    den += w * Lp[c * NTOK + q];
    h16x4 o = *reinterpret_cast<const h16x4*>(Oh + (size_t)c * NTOK * DH +
                                              (size_t)q * DH + dv);
    ax += w * (float)o.x; ay += w * (float)o.y;
    az += w * (float)o.z; aw += w * (float)o.w;
  }
  const float r = 1.f / den;
  float4 res; res.x = ax * r; res.y = ay * r; res.z = az * r; res.w = aw * r;
  *reinterpret_cast<float4*>(out + (size_t)q * DH + dv) = res;
}

extern "C" void kernel_launch(void* const* d_in, const int* in_sizes, int n_in,
                              void* d_out, int out_size, void* d_ws, size_t ws_size,
                              hipStream_t stream)
{
  const float* Q = (const float*)d_in[0];
  const float* K = (const float*)d_in[1];
  const float* V = (const float*)d_in[2];
  float* out = (float*)d_out;

  auto need = [](size_t ks) {   // f16 partials + f32 M/L
    return ks * (size_t)NTOK * DH * 2 + 2 * ks * (size_t)NTOK * 4;
  };
  int KS = (ws_size >= need(8)) ? 8 : (ws_size >= need(4)) ? 4 : 2;

  // K/V bf16 images live in d_out (4 MiB); combine overwrites d_out at the end.
  char* Kimg = (char*)d_out;
  char* Vimg = Kimg + (size_t)NTOK * 256;          // 2 MiB each

  _Float16* Oh = (_Float16*)d_ws;
  float* Mp = (float*)(Oh + (size_t)KS * NTOK * DH);
  float* Lp = Mp + (size_t)KS * NTOK;

  fa_prep<<<NTOK / KVB, 256, 0, stream>>>(K, V, Kimg, Vimg);
  fa_fwd<<<dim3(NTOK / QBLK, KS), 256, 0, stream>>>(Q, Kimg, Vimg, out, Oh,
                                                    Mp, Lp, KS, NTOK / KS);
  fa_combine<<<NTOK * DH / 4 / 256, 256, 0, stream>>>(Oh, Mp, Lp, out, KS);
}